// Round 8
// baseline (164.340 us; speedup 1.0000x reference)
//
#include <hip/hip_runtime.h>
#include <hip/hip_fp16.h>
#include <stdint.h>

#define NH 32   // heads (fixed by table shapes)

__device__ __forceinline__ float bf_to_f(uint16_t u)
{
    return __uint_as_float(((uint32_t)u) << 16);
}

// Async global->LDS 16B copy. LDS dest must be linear in lane order (rule #21):
// T is pre-swizzled in prep, both copy sides stay linear, swizzle applied on
// the LDS read address.
__device__ __forceinline__ void cp16(const void* g, void* l)
{
    __builtin_amdgcn_global_load_lds(
        (const __attribute__((address_space(1))) void*)g,
        (__attribute__((address_space(3))) void*)l, 16, 0, 0);
}

// Block-wide dtype sniff on first 4096 B of spd_table. bf16 N(0,1) never has
// exp field >= 0x89; fp32 low halves do with prob ~1. Returns 1 if fp32.
__device__ __forceinline__ int block_detect_fp32(const uint16_t* p16, int tid,
                                                 int* s_flag)
{
    if (tid == 0) *s_flag = 0;
    __syncthreads();
    const ushort4* p = (const ushort4*)p16;
    ushort4 a = p[tid * 2];
    ushort4 b = p[tid * 2 + 1];
    int big = 0;
    big |= (((a.x >> 7) & 0xFF) >= 0x89); big |= (((a.y >> 7) & 0xFF) >= 0x89);
    big |= (((a.z >> 7) & 0xFF) >= 0x89); big |= (((a.w >> 7) & 0xFF) >= 0x89);
    big |= (((b.x >> 7) & 0xFF) >= 0x89); big |= (((b.y >> 7) & 0xFF) >= 0x89);
    big |= (((b.z >> 7) & 0xFF) >= 0x89); big |= (((b.w >> 7) & 0xFF) >= 0x89);
    if (big) atomicOr(s_flag, 1);
    __syncthreads();
    return *s_flag;
}

// ---------------------------------------------------------------------------
// Fused prep (R12 layout: fp16 T).
//  threads [0, totalT): T16[d][e][k] = fp16( sum_h etab[e][h]*W[d,h,k] ).
//    Row = 32 halves = 64 B = 4 16-B groups. Content group g = k>>3 stored at
//    slot g ^ ((e>>1)&3); a read of content m at slot m^((e>>1)&3) lands on
//    bank-quad (e&1)<<2 | (m ^ ((e>>1)&3)) — bijective in e&7 at fixed m.
//    fp16 numerically safe: |T| <~ 30, rel err 2^-11 (passed, absmax 0.5).
//  threads [totalT, totalT+spd_n): spdT[h][s] = spd[s][h] fp32 (transposed).
// ---------------------------------------------------------------------------
__global__ __launch_bounds__(256) void prep(
    const void* __restrict__ edge_table,
    const void* __restrict__ W,
    const void* __restrict__ spd,
    uint16_t* __restrict__ T16,
    float* __restrict__ spdT,
    int totalT, int spd_n)
{
    __shared__ int s_flag;
    const int tid = threadIdx.x;
    const int is_fp32 = block_detect_fp32((const uint16_t*)spd, tid, &s_flag);
    int g = blockIdx.x * 256 + tid;
    if (g < totalT) {
        int d = g >> 10, e = (g >> 5) & 31, k = g & 31;
        float acc = 0.f;
        if (is_fp32) {
            const float* et = (const float*)edge_table + e * NH;
            const float* w  = (const float*)W + d * NH * NH + k;
#pragma unroll
            for (int h = 0; h < NH; ++h) acc += et[h] * w[h * NH];
        } else {
            const uint16_t* et = (const uint16_t*)edge_table + e * NH;
            const uint16_t* w  = (const uint16_t*)W + d * NH * NH + k;
#pragma unroll
            for (int h = 0; h < NH; ++h) acc += bf_to_f(et[h]) * bf_to_f(w[h * NH]);
        }
        int slot = (k >> 3) ^ ((e >> 1) & 3);              // XOR bank swizzle
        int idx  = (((d << 5) | e) << 5) + (slot << 3) + (k & 7);
        __half hv = __float2half(acc);
        T16[idx] = *(const uint16_t*)&hv;
    } else {
        int i = g - totalT;
        if (i < spd_n) {
            float v = is_fp32 ? ((const float*)spd)[i]
                              : bf_to_f(((const uint16_t*)spd)[i]);
            int s = i >> 5, h = i & 31;                    // input [s][h]
            spdT[h * (spd_n >> 5) + s] = v;                // output [h][s]
        }
    }
}

// ---------------------------------------------------------------------------
// Main kernel (R14 = R12 gather + DOUBLED OCCUPANCY).
// Session history: every schedule at 8 waves/CU (2 blocks x 40-72 KiB) lands
// at bond2d 26.5-32 us vs a ~13-19 us component model (writes 10.6 + LDS 3.8
// + VALU 1.7 + edge 1.5). Reordering one wave's instructions failed three
// ways (R11 store-first: vmcnt false coupling; R13 finer tiles: -3 us).
// The untouched knob is the WAVE POOL: with 8 waves/CU, a wave entering its
// 64-store drain has 1 other wave per SIMD to cover it, and same-block waves
// drain phase-correlated. fp16 T made LDS exactly 40 KiB (32 T + 8 spd) ->
// 4 blocks/CU fits 160 KiB exactly: 16 waves/CU, every wave independent
// (grid 1024 = all resident, one 256-pair tile each, no persistence loop ->
// simpler, fewer VGPR; staging x1024 = 41 MB from L2/L3 ~ 1.2 us, noise).
// Gather-phase waves now statistically cover store-phase waves (TLP).
// ---------------------------------------------------------------------------
__global__ __launch_bounds__(256, 4) void bond2d(
    const int* __restrict__ spatial,
    const int* __restrict__ edge,
    const float4* __restrict__ SgT,      // spdT as float4, NH*ns floats
    const float4* __restrict__ Tg,       // pre-swizzled fp16 T as float4
    float* __restrict__ out,
    int npairs, int D, int ns)
{
    __shared__ float4 Tl[2048];          // 32 KiB: D(<=16) x 32 e x 32 k fp16
    __shared__ float4 Sl4[512];          // 8 KiB : 32 h x 64 s fp32
    const float* Sl = (const float*)Sl4;

    const int t = threadIdx.x;
    const bool small_ns = (ns <= 64);
    const float* SgTf = (const float*)SgT;

    // ---- stage T (D*128 float4) + spd ----
    for (int i = t; i < D * 128; i += 256)
        cp16(Tg + i, Tl + i);
    if (small_ns) {
        const int nsf4 = (NH * ns) >> 2;
        for (int i = t; i < nsf4; i += 256)
            cp16(SgT + i, Sl4 + i);
    }

    // ---- own-tile loads issued before the barrier: land under the stage ----
    const int  pc  = blockIdx.x * 256 + t;
    const bool vc  = (pc < npairs);
    const int  pcc = vc ? pc : 0;
    const int  sc  = spatial[pcc];
    int4 c0, c1, c2, c3;
    if (D == 16) {
        const int4* er = (const int4*)(edge + (size_t)pcc * 16);
        c0 = er[0]; c1 = er[1]; c2 = er[2]; c3 = er[3];
    }

    __syncthreads();                     // cp16s drained (vmcnt0 at barrier)

    if (D == 16) {
        int ev[16];
        ev[0]=c0.x;  ev[1]=c0.y;  ev[2]=c0.z;  ev[3]=c0.w;
        ev[4]=c1.x;  ev[5]=c1.y;  ev[6]=c1.z;  ev[7]=c1.w;
        ev[8]=c2.x;  ev[9]=c2.y;  ev[10]=c2.z; ev[11]=c2.w;
        ev[12]=c3.x; ev[13]=c3.y; ev[14]=c3.z; ev[15]=c3.w;

        float acc[32];
#pragma unroll
        for (int k = 0; k < 32; ++k) acc[k] = 0.f;

        const char* Tb = (const char*)Tl;
#pragma unroll
        for (int d = 0; d < 16; ++d) {
            int e    = ev[d];
            int base = (((d << 5) | e) << 6);      // bytes (64 B/row)
            int sw   = ((e >> 1) & 3) << 4;
#pragma unroll
            for (int m = 0; m < 4; ++m) {
                uint4 w = *(const uint4*)(Tb + base + ((m << 4) ^ sw));
                float2 f0 = __half22float2(*(const __half2*)&w.x);
                float2 f1 = __half22float2(*(const __half2*)&w.y);
                float2 f2 = __half22float2(*(const __half2*)&w.z);
                float2 f3 = __half22float2(*(const __half2*)&w.w);
                acc[8*m+0] += f0.x; acc[8*m+1] += f0.y;
                acc[8*m+2] += f1.x; acc[8*m+3] += f1.y;
                acc[8*m+4] += f2.x; acc[8*m+5] += f2.y;
                acc[8*m+6] += f3.x; acc[8*m+7] += f3.y;
            }
        }

        if (vc) {
            const float rs = 1.0f / (sc ? (float)sc : 1.0f);
            float* o0 = out + pc;                        // phi_spd
            float* o1 = out + (size_t)NH * npairs + pc;  // phi_edge
            const float* sA = Sl + sc;
#pragma unroll
            for (int k = 0; k < 32; ++k) {
                o1[(size_t)k * npairs] = acc[k] * rs;
                o0[(size_t)k * npairs] =
                    small_ns ? sA[k * ns] : SgTf[(size_t)k * ns + sc];
            }
        }
    } else {
        // generic-D fallback (not hit on this bench)
        int  p  = pc;
        bool v  = vc;
        int  pp = pcc;
        int  s  = sc;
        const int* erow = edge + (size_t)pp * D;

        float acc[32];
#pragma unroll
        for (int k = 0; k < 32; ++k) acc[k] = 0.f;

        const char* Tb = (const char*)Tl;
        for (int d = 0; d < D; ++d) {
            int e    = erow[d];
            int base = (((d << 5) | e) << 6);
            int sw   = ((e >> 1) & 3) << 4;
#pragma unroll
            for (int m = 0; m < 4; ++m) {
                uint4 w = *(const uint4*)(Tb + base + ((m << 4) ^ sw));
                float2 f0 = __half22float2(*(const __half2*)&w.x);
                float2 f1 = __half22float2(*(const __half2*)&w.y);
                float2 f2 = __half22float2(*(const __half2*)&w.z);
                float2 f3 = __half22float2(*(const __half2*)&w.w);
                acc[8*m+0] += f0.x; acc[8*m+1] += f0.y;
                acc[8*m+2] += f1.x; acc[8*m+3] += f1.y;
                acc[8*m+4] += f2.x; acc[8*m+5] += f2.y;
                acc[8*m+6] += f3.x; acc[8*m+7] += f3.y;
            }
        }

        if (v) {
            const float rs = 1.0f / (s ? (float)s : 1.0f);
            float* o0 = out + p;
            float* o1 = out + (size_t)NH * npairs + p;
            const float* sA = Sl + s;
#pragma unroll
            for (int k = 0; k < 32; ++k) {
                o1[(size_t)k * npairs] = acc[k] * rs;
                o0[(size_t)k * npairs] =
                    small_ns ? sA[k * ns] : SgTf[(size_t)k * ns + s];
            }
        }
    }
}

extern "C" void kernel_launch(void* const* d_in, const int* in_sizes, int n_in,
                              void* d_out, int out_size, void* d_ws, size_t ws_size,
                              hipStream_t stream) {
    // dict order: [0]=spatial_pos [1]=edge_input [2]=max_dist [3]=spd_table
    //             [4]=edge_table  [5]=edge_dis_weight
    const int* spatial = (const int*)d_in[0];
    const int* edge    = (const int*)d_in[1];
    const void* spd    = d_in[3];
    const void* etab   = d_in[4];
    const void* W      = d_in[5];

    long long npairs = in_sizes[0];
    long long etot   = in_sizes[1];
    int D = (int)(etot / (npairs > 0 ? npairs : 1));
    if (D < 1) D = 1;
    if (D > 16) D = 16;
    int spd_n  = in_sizes[3];
    int ns     = spd_n >> 5;          // spatial vocab (64 here)
    int totalT = D * 1024;

    uint16_t* T16 = (uint16_t*)d_ws;            // D*1024 fp16, pre-swizzled
    float*    spdT = (float*)(T16 + totalT);    // spd_n fp32, transposed [h][s]

    prep<<<(totalT + spd_n + 255) / 256, 256, 0, stream>>>(
        etab, W, spd, T16, spdT, totalT, spd_n);

    int nblk = (int)((npairs + 255) / 256);
    bond2d<<<nblk, 256, 0, stream>>>(spatial, edge, (const float4*)spdT,
                                     (const float4*)T16, (float*)d_out,
                                     (int)npairs, D, ns);
}

// Round 9
// 100.750 us; speedup vs baseline: 1.6312x; 1.6312x over previous
//
#include <hip/hip_runtime.h>
#include <hip/hip_fp16.h>
#include <stdint.h>

#define NH 32   // heads (fixed by table shapes)

__device__ __forceinline__ float bf_to_f(uint16_t u)
{
    return __uint_as_float(((uint32_t)u) << 16);
}

// Async global->LDS 16B copy. LDS dest must be linear in lane order (rule #21):
// T is pre-swizzled in prep, both copy sides stay linear, swizzle applied on
// the LDS read address.
__device__ __forceinline__ void cp16(const void* g, void* l)
{
    __builtin_amdgcn_global_load_lds(
        (const __attribute__((address_space(1))) void*)g,
        (__attribute__((address_space(3))) void*)l, 16, 0, 0);
}

// Block-wide dtype sniff on first 4096 B of spd_table. bf16 N(0,1) never has
// exp field >= 0x89; fp32 low halves do with prob ~1. Returns 1 if fp32.
__device__ __forceinline__ int block_detect_fp32(const uint16_t* p16, int tid,
                                                 int* s_flag)
{
    if (tid == 0) *s_flag = 0;
    __syncthreads();
    const ushort4* p = (const ushort4*)p16;
    ushort4 a = p[tid * 2];
    ushort4 b = p[tid * 2 + 1];
    int big = 0;
    big |= (((a.x >> 7) & 0xFF) >= 0x89); big |= (((a.y >> 7) & 0xFF) >= 0x89);
    big |= (((a.z >> 7) & 0xFF) >= 0x89); big |= (((a.w >> 7) & 0xFF) >= 0x89);
    big |= (((b.x >> 7) & 0xFF) >= 0x89); big |= (((b.y >> 7) & 0xFF) >= 0x89);
    big |= (((b.z >> 7) & 0xFF) >= 0x89); big |= (((b.w >> 7) & 0xFF) >= 0x89);
    if (big) atomicOr(s_flag, 1);
    __syncthreads();
    return *s_flag;
}

// ---------------------------------------------------------------------------
// Fused prep (R12 layout: fp16 T).
//  threads [0, totalT): T16[d][e][k] = fp16( sum_h etab[e][h]*W[d,h,k] ).
//    Row = 32 halves = 64 B = 4 16-B groups. Content group g = k>>3 stored at
//    slot g ^ ((e>>1)&3); a read of content m at slot m^((e>>1)&3) lands on
//    bank-quad (e&1)<<2 | (m ^ ((e>>1)&3)) — bijective in e&7 at fixed m.
//  threads [totalT, totalT+spd_n): spdT[h][s] = spd[s][h] fp32 (transposed).
// ---------------------------------------------------------------------------
__global__ __launch_bounds__(256) void prep(
    const void* __restrict__ edge_table,
    const void* __restrict__ W,
    const void* __restrict__ spd,
    uint16_t* __restrict__ T16,
    float* __restrict__ spdT,
    int totalT, int spd_n)
{
    __shared__ int s_flag;
    const int tid = threadIdx.x;
    const int is_fp32 = block_detect_fp32((const uint16_t*)spd, tid, &s_flag);
    int g = blockIdx.x * 256 + tid;
    if (g < totalT) {
        int d = g >> 10, e = (g >> 5) & 31, k = g & 31;
        float acc = 0.f;
        if (is_fp32) {
            const float* et = (const float*)edge_table + e * NH;
            const float* w  = (const float*)W + d * NH * NH + k;
#pragma unroll
            for (int h = 0; h < NH; ++h) acc += et[h] * w[h * NH];
        } else {
            const uint16_t* et = (const uint16_t*)edge_table + e * NH;
            const uint16_t* w  = (const uint16_t*)W + d * NH * NH + k;
#pragma unroll
            for (int h = 0; h < NH; ++h) acc += bf_to_f(et[h]) * bf_to_f(w[h * NH]);
        }
        int slot = (k >> 3) ^ ((e >> 1) & 3);              // XOR bank swizzle
        int idx  = (((d << 5) | e) << 5) + (slot << 3) + (k & 7);
        __half hv = __float2half(acc);
        T16[idx] = *(const uint16_t*)&hv;
    } else {
        int i = g - totalT;
        if (i < spd_n) {
            float v = is_fp32 ? ((const float*)spd)[i]
                              : bf_to_f(((const uint16_t*)spd)[i]);
            int s = i >> 5, h = i & 31;                    // input [s][h]
            spdT[h * (spd_n >> 5) + s] = v;                // output [h][s]
        }
    }
}

// ---------------------------------------------------------------------------
// Main kernel (R15 = R12 structure EXACTLY + fp16 packed accumulation).
// Structure lessons (hard-won): R9/R14 (more concurrent store generations)
// inflate HBM traffic ~4x and halve BW — keep grid 512 persistent,
// 2 tiles/block, stage-once, loads-first/stores-last. R11/R13 intra-wave
// store reordering: regressed. The remaining co-dominant serial term is
// VALU: the fp16->f32 unpack costs ~(8 cvt + 8 add) per 16B LDS read =
// ~1000 instr/thread ~ 9-14 us/CU (R14's VALUBusy 10% over 88 us = 8.8 us
// absolute). Fix: d-sum accumulates IN fp16 via v_pk_add_f16 (__hadd2,
// 2 k-lanes/instr, zero cvt in loop), two chains of 8 d's for error
// control, one convert per 8-k group: ~88 instr per m-group vs ~256,
// per-thread VALU ~1024 -> ~380. Precision: chains of 8, |partials|<~80,
// adds <~0.3 worst-case on top of current 0.5 absmax.
// LDS 40 KiB, grid 512 -> 2 blocks/CU, zero steady-state barriers.
// ---------------------------------------------------------------------------
__global__ __launch_bounds__(256, 2) void bond2d(
    const int* __restrict__ spatial,
    const int* __restrict__ edge,
    const float4* __restrict__ SgT,      // spdT as float4, NH*ns floats
    const float4* __restrict__ Tg,       // pre-swizzled fp16 T as float4
    float* __restrict__ out,
    int npairs, int D, int ns, int ntiles, int gridsz)
{
    __shared__ float4 Tl[2048];          // 32 KiB: D(<=16) x 32 e x 32 k fp16
    __shared__ float4 Sl4[512];          // 8 KiB : 32 h x 64 s fp32
    const float* Sl = (const float*)Sl4;

    const int t = threadIdx.x;
    const bool small_ns = (ns <= 64);
    const float* SgTf = (const float*)SgT;

    // ---- stage T (D*128 float4) + spd once; the only barrier ----
    for (int i = t; i < D * 128; i += 256)
        cp16(Tg + i, Tl + i);
    if (small_ns) {
        const int nsf4 = (NH * ns) >> 2;
        for (int i = t; i < nsf4; i += 256)
            cp16(SgT + i, Sl4 + i);
    }

    // ---- prefetch tile 0 while the stage drains ----
    int tile = blockIdx.x;
    int  pc  = tile * 256 + t;
    bool vc  = (pc < npairs);
    int  pcc = vc ? pc : 0;
    int  sc  = spatial[pcc];
    int4 c0, c1, c2, c3;
    if (D == 16) {
        const int4* er = (const int4*)(edge + (size_t)pcc * 16);
        c0 = er[0]; c1 = er[1]; c2 = er[2]; c3 = er[3];
    }

    __syncthreads();                     // cp16s drained (vmcnt0 at barrier)

    if (D == 16) {
        for (;;) {
            // issue next tile's loads now — they land under the gather
            const int  tn  = tile + gridsz;
            const bool hn  = (tn < ntiles);
            int  pn = tn * 256 + t;
            bool vn = hn && (pn < npairs);
            int  pnn = vn ? pn : 0;
            int  sn = 0;
            int4 n0, n1, n2, n3;
            if (hn) {
                sn = spatial[pnn];
                const int4* er = (const int4*)(edge + (size_t)pnn * 16);
                n0 = er[0]; n1 = er[1]; n2 = er[2]; n3 = er[3];
            }

            int ev[16];
            ev[0]=c0.x;  ev[1]=c0.y;  ev[2]=c0.z;  ev[3]=c0.w;
            ev[4]=c1.x;  ev[5]=c1.y;  ev[6]=c1.z;  ev[7]=c1.w;
            ev[8]=c2.x;  ev[9]=c2.y;  ev[10]=c2.z; ev[11]=c2.w;
            ev[12]=c3.x; ev[13]=c3.y; ev[14]=c3.z; ev[15]=c3.w;

            float acc[32];
            const char* Tb = (const char*)Tl;
#pragma unroll
            for (int m = 0; m < 4; ++m) {
                // chain 1: d = 0..7 in fp16
                __half2 h0 = __float2half2_rn(0.f), h1 = h0, h2 = h0, h3 = h0;
#pragma unroll
                for (int d = 0; d < 8; ++d) {
                    int e    = ev[d];
                    int base = (((d << 5) | e) << 6);
                    int sw   = ((e >> 1) & 3) << 4;
                    uint4 w = *(const uint4*)(Tb + base + ((m << 4) ^ sw));
                    h0 = __hadd2(h0, *(const __half2*)&w.x);
                    h1 = __hadd2(h1, *(const __half2*)&w.y);
                    h2 = __hadd2(h2, *(const __half2*)&w.z);
                    h3 = __hadd2(h3, *(const __half2*)&w.w);
                }
                float2 f0 = __half22float2(h0);
                float2 f1 = __half22float2(h1);
                float2 f2 = __half22float2(h2);
                float2 f3 = __half22float2(h3);
                // chain 2: d = 8..15 in fp16
                h0 = __float2half2_rn(0.f); h1 = h0; h2 = h0; h3 = h0;
#pragma unroll
                for (int d = 8; d < 16; ++d) {
                    int e    = ev[d];
                    int base = (((d << 5) | e) << 6);
                    int sw   = ((e >> 1) & 3) << 4;
                    uint4 w = *(const uint4*)(Tb + base + ((m << 4) ^ sw));
                    h0 = __hadd2(h0, *(const __half2*)&w.x);
                    h1 = __hadd2(h1, *(const __half2*)&w.y);
                    h2 = __hadd2(h2, *(const __half2*)&w.z);
                    h3 = __hadd2(h3, *(const __half2*)&w.w);
                }
                float2 g0 = __half22float2(h0);
                float2 g1 = __half22float2(h1);
                float2 g2 = __half22float2(h2);
                float2 g3 = __half22float2(h3);
                acc[8*m+0] = f0.x + g0.x; acc[8*m+1] = f0.y + g0.y;
                acc[8*m+2] = f1.x + g1.x; acc[8*m+3] = f1.y + g1.y;
                acc[8*m+4] = f2.x + g2.x; acc[8*m+5] = f2.y + g2.y;
                acc[8*m+6] = f3.x + g3.x; acc[8*m+7] = f3.y + g3.y;
            }

            if (vc) {
                const float rs = 1.0f / (sc ? (float)sc : 1.0f);
                float* o0 = out + pc;                        // phi_spd
                float* o1 = out + (size_t)NH * npairs + pc;  // phi_edge
                const float* sA = Sl + sc;
#pragma unroll
                for (int k = 0; k < 32; ++k) {
                    o1[(size_t)k * npairs] = acc[k] * rs;
                    o0[(size_t)k * npairs] =
                        small_ns ? sA[k * ns] : SgTf[(size_t)k * ns + sc];
                }
            }

            if (!hn) break;
            tile = tn; pc = pn; vc = vn; pcc = pnn; sc = sn;
            c0 = n0; c1 = n1; c2 = n2; c3 = n3;
        }
    } else {
        // generic-D fallback (not hit on this bench) — fp32 accumulate
        for (; tile < ntiles; tile += gridsz) {
            int  p  = tile * 256 + t;
            bool v  = (p < npairs);
            int  pp = v ? p : 0;
            int  s  = spatial[pp];
            const int* erow = edge + (size_t)pp * D;

            float acc[32];
#pragma unroll
            for (int k = 0; k < 32; ++k) acc[k] = 0.f;

            const char* Tb = (const char*)Tl;
            for (int d = 0; d < D; ++d) {
                int e    = erow[d];
                int base = (((d << 5) | e) << 6);
                int sw   = ((e >> 1) & 3) << 4;
#pragma unroll
                for (int m = 0; m < 4; ++m) {
                    uint4 w = *(const uint4*)(Tb + base + ((m << 4) ^ sw));
                    float2 f0 = __half22float2(*(const __half2*)&w.x);
                    float2 f1 = __half22float2(*(const __half2*)&w.y);
                    float2 f2 = __half22float2(*(const __half2*)&w.z);
                    float2 f3 = __half22float2(*(const __half2*)&w.w);
                    acc[8*m+0] += f0.x; acc[8*m+1] += f0.y;
                    acc[8*m+2] += f1.x; acc[8*m+3] += f1.y;
                    acc[8*m+4] += f2.x; acc[8*m+5] += f2.y;
                    acc[8*m+6] += f3.x; acc[8*m+7] += f3.y;
                }
            }

            if (v) {
                const float rs = 1.0f / (s ? (float)s : 1.0f);
                float* o0 = out + p;
                float* o1 = out + (size_t)NH * npairs + p;
                const float* sA = Sl + s;
#pragma unroll
                for (int k = 0; k < 32; ++k) {
                    o1[(size_t)k * npairs] = acc[k] * rs;
                    o0[(size_t)k * npairs] =
                        small_ns ? sA[k * ns] : SgTf[(size_t)k * ns + s];
                }
            }
        }
    }
}

extern "C" void kernel_launch(void* const* d_in, const int* in_sizes, int n_in,
                              void* d_out, int out_size, void* d_ws, size_t ws_size,
                              hipStream_t stream) {
    // dict order: [0]=spatial_pos [1]=edge_input [2]=max_dist [3]=spd_table
    //             [4]=edge_table  [5]=edge_dis_weight
    const int* spatial = (const int*)d_in[0];
    const int* edge    = (const int*)d_in[1];
    const void* spd    = d_in[3];
    const void* etab   = d_in[4];
    const void* W      = d_in[5];

    long long npairs = in_sizes[0];
    long long etot   = in_sizes[1];
    int D = (int)(etot / (npairs > 0 ? npairs : 1));
    if (D < 1) D = 1;
    if (D > 16) D = 16;
    int spd_n  = in_sizes[3];
    int ns     = spd_n >> 5;          // spatial vocab (64 here)
    int totalT = D * 1024;

    uint16_t* T16 = (uint16_t*)d_ws;            // D*1024 fp16, pre-swizzled
    float*    spdT = (float*)(T16 + totalT);    // spd_n fp32, transposed [h][s]

    prep<<<(totalT + spd_n + 255) / 256, 256, 0, stream>>>(
        etab, W, spd, T16, spdT, totalT, spd_n);

    int ntiles = (int)((npairs + 255) / 256);
    int gridsz = ntiles < 512 ? ntiles : 512;
    bond2d<<<gridsz, 256, 0, stream>>>(spatial, edge, (const float4*)spdT,
                                       (const float4*)T16, (float*)d_out,
                                       (int)npairs, D, ns, ntiles, gridsz);
}

// Round 10
// 98.531 us; speedup vs baseline: 1.6679x; 1.0225x over previous
//
#include <hip/hip_runtime.h>
#include <hip/hip_fp16.h>
#include <stdint.h>

#define NH 32   // heads (fixed by table shapes)

__device__ __forceinline__ float bf_to_f(uint16_t u)
{
    return __uint_as_float(((uint32_t)u) << 16);
}

// Async global->LDS 16B copy. LDS dest must be linear in lane order (rule #21):
// T is pre-swizzled in prep, both copy sides stay linear, swizzle applied on
// the LDS read address.
__device__ __forceinline__ void cp16(const void* g, void* l)
{
    __builtin_amdgcn_global_load_lds(
        (const __attribute__((address_space(1))) void*)g,
        (__attribute__((address_space(3))) void*)l, 16, 0, 0);
}

// Block-wide dtype sniff on first 4096 B of spd_table. bf16 N(0,1) never has
// exp field >= 0x89; fp32 low halves do with prob ~1. Returns 1 if fp32.
__device__ __forceinline__ int block_detect_fp32(const uint16_t* p16, int tid,
                                                 int* s_flag)
{
    if (tid == 0) *s_flag = 0;
    __syncthreads();
    const ushort4* p = (const ushort4*)p16;
    ushort4 a = p[tid * 2];
    ushort4 b = p[tid * 2 + 1];
    int big = 0;
    big |= (((a.x >> 7) & 0xFF) >= 0x89); big |= (((a.y >> 7) & 0xFF) >= 0x89);
    big |= (((a.z >> 7) & 0xFF) >= 0x89); big |= (((a.w >> 7) & 0xFF) >= 0x89);
    big |= (((b.x >> 7) & 0xFF) >= 0x89); big |= (((b.y >> 7) & 0xFF) >= 0x89);
    big |= (((b.z >> 7) & 0xFF) >= 0x89); big |= (((b.w >> 7) & 0xFF) >= 0x89);
    if (big) atomicOr(s_flag, 1);
    __syncthreads();
    return *s_flag;
}

// ---------------------------------------------------------------------------
// Fused prep (R12 layout: fp16 T).
//  threads [0, totalT): T16[d][e][k] = fp16( sum_h etab[e][h]*W[d,h,k] ).
//    Row = 32 halves = 64 B = 4 16-B groups. Content group g = k>>3 stored at
//    slot g ^ ((e>>1)&3); a read of content m at slot m^((e>>1)&3) lands on
//    bank-quad (e&1)<<2 | (m ^ ((e>>1)&3)) — bijective in e&7 at fixed m.
//  threads [totalT, totalT+spd_n): spdT[h][s] = spd[s][h] fp32 (transposed).
// ---------------------------------------------------------------------------
__global__ __launch_bounds__(256) void prep(
    const void* __restrict__ edge_table,
    const void* __restrict__ W,
    const void* __restrict__ spd,
    uint16_t* __restrict__ T16,
    float* __restrict__ spdT,
    int totalT, int spd_n)
{
    __shared__ int s_flag;
    const int tid = threadIdx.x;
    const int is_fp32 = block_detect_fp32((const uint16_t*)spd, tid, &s_flag);
    int g = blockIdx.x * 256 + tid;
    if (g < totalT) {
        int d = g >> 10, e = (g >> 5) & 31, k = g & 31;
        float acc = 0.f;
        if (is_fp32) {
            const float* et = (const float*)edge_table + e * NH;
            const float* w  = (const float*)W + d * NH * NH + k;
#pragma unroll
            for (int h = 0; h < NH; ++h) acc += et[h] * w[h * NH];
        } else {
            const uint16_t* et = (const uint16_t*)edge_table + e * NH;
            const uint16_t* w  = (const uint16_t*)W + d * NH * NH + k;
#pragma unroll
            for (int h = 0; h < NH; ++h) acc += bf_to_f(et[h]) * bf_to_f(w[h * NH]);
        }
        int slot = (k >> 3) ^ ((e >> 1) & 3);              // XOR bank swizzle
        int idx  = (((d << 5) | e) << 5) + (slot << 3) + (k & 7);
        __half hv = __float2half(acc);
        T16[idx] = *(const uint16_t*)&hv;
    } else {
        int i = g - totalT;
        if (i < spd_n) {
            float v = is_fp32 ? ((const float*)spd)[i]
                              : bf_to_f(((const uint16_t*)spd)[i]);
            int s = i >> 5, h = i & 31;                    // input [s][h]
            spdT[h * (spd_n >> 5) + s] = v;                // output [h][s]
        }
    }
}

// ---------------------------------------------------------------------------
// Main kernel (R16 = R15 gather + single-tile pair-duo + rolling float2
// stores).
// Key insight revising R11's failure: stores couple only with GLOBAL loads
// (both vmcnt); ds_read uses lgkmcnt. R11/R13 regressed because next-tile
// global loads followed the stores. A SINGLE-TILE block has no global loads
// after the stage barrier (edge/spatial were issued before it and drained
// into registers by its vmcnt(0)) -> rolling stores are hazard-free here.
// Changes vs R15 (geometry/occupancy/staging identical: grid 512, 40 KiB
// LDS, 2 blocks/CU, 8 waves/CU):
//  - 2 ADJACENT pairs per thread -> all stores float2: 64 store instrs vs
//    128 scalar, 512 B contiguous per wave-store burst, edge loads 128 B
//    contiguous per thread.
//  - rolling drain: phi_spd stores right after the barrier (33.5 MB in
//    flight under the whole gather); each m-group's phi_edge half stored
//    as soon as computed (4 bursts interleaved into the gather).
//  - two independent fp16 hadd2 chains (pair0/pair1) double LDS/VALU ILP.
// ---------------------------------------------------------------------------
__global__ __launch_bounds__(256, 2) void bond2d(
    const int* __restrict__ spatial,
    const int* __restrict__ edge,
    const float4* __restrict__ SgT,      // spdT as float4, NH*ns floats
    const float4* __restrict__ Tg,       // pre-swizzled fp16 T as float4
    float* __restrict__ out,
    int npairs, int D, int ns)
{
    __shared__ float4 Tl[2048];          // 32 KiB: D(<=16) x 32 e x 32 k fp16
    __shared__ float4 Sl4[512];          // 8 KiB : 32 h x 64 s fp32
    const float* Sl = (const float*)Sl4;

    const int t = threadIdx.x;
    const bool small_ns = (ns <= 64);
    const float* SgTf = (const float*)SgT;

    // ---- stage T (D*128 float4) + spd; the only barrier ----
    for (int i = t; i < D * 128; i += 256)
        cp16(Tg + i, Tl + i);
    if (small_ns) {
        const int nsf4 = (NH * ns) >> 2;
        for (int i = t; i < nsf4; i += 256)
            cp16(SgT + i, Sl4 + i);
    }

    // ---- own-pair loads issued before the barrier: land under the stage,
    //      and are drained into registers by the barrier's vmcnt(0) ----
    const int  base0 = (blockIdx.x * 256 + t) * 2;
    const bool v0 = (base0 < npairs);
    const bool v1 = (base0 + 1 < npairs);
    const int  p0 = v0 ? base0 : 0;
    const int  p1 = v1 ? (base0 + 1) : p0;
    const int  s0 = spatial[p0];
    const int  s1 = spatial[p1];
    int4 a0, a1, a2, a3, b0, b1, b2, b3;
    if (D == 16) {
        const int4* er0 = (const int4*)(edge + (size_t)p0 * 16);
        const int4* er1 = (const int4*)(edge + (size_t)p1 * 16);
        a0 = er0[0]; a1 = er0[1]; a2 = er0[2]; a3 = er0[3];
        b0 = er1[0]; b1 = er1[1]; b2 = er1[2]; b3 = er1[3];
    }

    __syncthreads();                     // cp16s + our loads drained

    const float rs0 = 1.0f / (s0 ? (float)s0 : 1.0f);
    const float rs1 = 1.0f / (s1 ? (float)s1 : 1.0f);
    float* o0 = out + base0;                         // phi_spd
    float* o1 = out + (size_t)NH * npairs + base0;   // phi_edge
    const bool vec = v1 && !(npairs & 1);            // float2-safe

    if (D == 16) {
        // ---- phi_spd stores first: in flight under the whole gather ----
        if (small_ns) {
            const float* sA = Sl + s0;
            const float* sB = Sl + s1;
            if (vec) {
#pragma unroll
                for (int k = 0; k < 32; ++k)
                    *(float2*)(o0 + (size_t)k * npairs) =
                        make_float2(sA[k * ns], sB[k * ns]);
            } else if (v0) {
#pragma unroll
                for (int k = 0; k < 32; ++k) {
                    o0[(size_t)k * npairs] = sA[k * ns];
                    if (v1) o0[(size_t)k * npairs + 1] = sB[k * ns];
                }
            }
        } else if (v0) {
            // cold path: gather to regs first (loads), then store
            float g0[32], g1[32];
#pragma unroll
            for (int k = 0; k < 32; ++k) {
                g0[k] = SgTf[(size_t)k * ns + s0];
                g1[k] = SgTf[(size_t)k * ns + s1];
            }
#pragma unroll
            for (int k = 0; k < 32; ++k) {
                o0[(size_t)k * npairs] = g0[k];
                if (v1) o0[(size_t)k * npairs + 1] = g1[k];
            }
        }

        int ev0[16], ev1[16];
        ev0[0]=a0.x;  ev0[1]=a0.y;  ev0[2]=a0.z;  ev0[3]=a0.w;
        ev0[4]=a1.x;  ev0[5]=a1.y;  ev0[6]=a1.z;  ev0[7]=a1.w;
        ev0[8]=a2.x;  ev0[9]=a2.y;  ev0[10]=a2.z; ev0[11]=a2.w;
        ev0[12]=a3.x; ev0[13]=a3.y; ev0[14]=a3.z; ev0[15]=a3.w;
        ev1[0]=b0.x;  ev1[1]=b0.y;  ev1[2]=b0.z;  ev1[3]=b0.w;
        ev1[4]=b1.x;  ev1[5]=b1.y;  ev1[6]=b1.z;  ev1[7]=b1.w;
        ev1[8]=b2.x;  ev1[9]=b2.y;  ev1[10]=b2.z; ev1[11]=b2.w;
        ev1[12]=b3.x; ev1[13]=b3.y; ev1[14]=b3.z; ev1[15]=b3.w;

        const char* Tb = (const char*)Tl;
#pragma unroll
        for (int m = 0; m < 4; ++m) {
            // pair0/pair1 chains, d = 0..7 in fp16 (independent -> ILP)
            __half2 ha0 = __float2half2_rn(0.f), ha1 = ha0, ha2 = ha0, ha3 = ha0;
            __half2 hb0 = ha0, hb1 = ha0, hb2 = ha0, hb3 = ha0;
#pragma unroll
            for (int d = 0; d < 8; ++d) {
                int e0 = ev0[d], e1 = ev1[d];
                uint4 w0 = *(const uint4*)(Tb + (((d << 5) | e0) << 6)
                                              + ((m << 4) ^ (((e0 >> 1) & 3) << 4)));
                uint4 w1 = *(const uint4*)(Tb + (((d << 5) | e1) << 6)
                                              + ((m << 4) ^ (((e1 >> 1) & 3) << 4)));
                ha0 = __hadd2(ha0, *(const __half2*)&w0.x);
                ha1 = __hadd2(ha1, *(const __half2*)&w0.y);
                ha2 = __hadd2(ha2, *(const __half2*)&w0.z);
                ha3 = __hadd2(ha3, *(const __half2*)&w0.w);
                hb0 = __hadd2(hb0, *(const __half2*)&w1.x);
                hb1 = __hadd2(hb1, *(const __half2*)&w1.y);
                hb2 = __hadd2(hb2, *(const __half2*)&w1.z);
                hb3 = __hadd2(hb3, *(const __half2*)&w1.w);
            }
            float2 fa0 = __half22float2(ha0), fa1 = __half22float2(ha1);
            float2 fa2 = __half22float2(ha2), fa3 = __half22float2(ha3);
            float2 fb0 = __half22float2(hb0), fb1 = __half22float2(hb1);
            float2 fb2 = __half22float2(hb2), fb3 = __half22float2(hb3);
            // chains d = 8..15
            ha0 = __float2half2_rn(0.f); ha1 = ha0; ha2 = ha0; ha3 = ha0;
            hb0 = ha0; hb1 = ha0; hb2 = ha0; hb3 = ha0;
#pragma unroll
            for (int d = 8; d < 16; ++d) {
                int e0 = ev0[d], e1 = ev1[d];
                uint4 w0 = *(const uint4*)(Tb + (((d << 5) | e0) << 6)
                                              + ((m << 4) ^ (((e0 >> 1) & 3) << 4)));
                uint4 w1 = *(const uint4*)(Tb + (((d << 5) | e1) << 6)
                                              + ((m << 4) ^ (((e1 >> 1) & 3) << 4)));
                ha0 = __hadd2(ha0, *(const __half2*)&w0.x);
                ha1 = __hadd2(ha1, *(const __half2*)&w0.y);
                ha2 = __hadd2(ha2, *(const __half2*)&w0.z);
                ha3 = __hadd2(ha3, *(const __half2*)&w0.w);
                hb0 = __hadd2(hb0, *(const __half2*)&w1.x);
                hb1 = __hadd2(hb1, *(const __half2*)&w1.y);
                hb2 = __hadd2(hb2, *(const __half2*)&w1.z);
                hb3 = __hadd2(hb3, *(const __half2*)&w1.w);
            }
            float2 ga0 = __half22float2(ha0), ga1 = __half22float2(ha1);
            float2 ga2 = __half22float2(ha2), ga3 = __half22float2(ha3);
            float2 gb0 = __half22float2(hb0), gb1 = __half22float2(hb1);
            float2 gb2 = __half22float2(hb2), gb3 = __half22float2(hb3);

            float r0[8], r1[8];
            r0[0] = fa0.x + ga0.x; r0[1] = fa0.y + ga0.y;
            r0[2] = fa1.x + ga1.x; r0[3] = fa1.y + ga1.y;
            r0[4] = fa2.x + ga2.x; r0[5] = fa2.y + ga2.y;
            r0[6] = fa3.x + ga3.x; r0[7] = fa3.y + ga3.y;
            r1[0] = fb0.x + gb0.x; r1[1] = fb0.y + gb0.y;
            r1[2] = fb1.x + gb1.x; r1[3] = fb1.y + gb1.y;
            r1[4] = fb2.x + gb2.x; r1[5] = fb2.y + gb2.y;
            r1[6] = fb3.x + gb3.x; r1[7] = fb3.y + gb3.y;

            // rolling phi_edge stores for this m-group (no global loads
            // follow in this kernel -> no vmcnt coupling hazard)
            if (vec) {
#pragma unroll
                for (int j = 0; j < 8; ++j)
                    *(float2*)(o1 + (size_t)(8 * m + j) * npairs) =
                        make_float2(r0[j] * rs0, r1[j] * rs1);
            } else if (v0) {
#pragma unroll
                for (int j = 0; j < 8; ++j) {
                    o1[(size_t)(8 * m + j) * npairs] = r0[j] * rs0;
                    if (v1) o1[(size_t)(8 * m + j) * npairs + 1] = r1[j] * rs1;
                }
            }
        }
    } else {
        // generic-D fallback (not hit on this bench) — fp32 accumulate
        if (!v0) return;
        const int* er0 = edge + (size_t)p0 * D;
        const int* er1 = edge + (size_t)p1 * D;

        float acc0[32], acc1[32];
#pragma unroll
        for (int k = 0; k < 32; ++k) { acc0[k] = 0.f; acc1[k] = 0.f; }

        const char* Tb = (const char*)Tl;
        for (int d = 0; d < D; ++d) {
            int e0 = er0[d], e1 = er1[d];
#pragma unroll
            for (int m = 0; m < 4; ++m) {
                uint4 w0 = *(const uint4*)(Tb + (((d << 5) | e0) << 6)
                                              + ((m << 4) ^ (((e0 >> 1) & 3) << 4)));
                uint4 w1 = *(const uint4*)(Tb + (((d << 5) | e1) << 6)
                                              + ((m << 4) ^ (((e1 >> 1) & 3) << 4)));
                float2 f0 = __half22float2(*(const __half2*)&w0.x);
                float2 f1 = __half22float2(*(const __half2*)&w0.y);
                float2 f2 = __half22float2(*(const __half2*)&w0.z);
                float2 f3 = __half22float2(*(const __half2*)&w0.w);
                acc0[8*m+0] += f0.x; acc0[8*m+1] += f0.y;
                acc0[8*m+2] += f1.x; acc0[8*m+3] += f1.y;
                acc0[8*m+4] += f2.x; acc0[8*m+5] += f2.y;
                acc0[8*m+6] += f3.x; acc0[8*m+7] += f3.y;
                f0 = __half22float2(*(const __half2*)&w1.x);
                f1 = __half22float2(*(const __half2*)&w1.y);
                f2 = __half22float2(*(const __half2*)&w1.z);
                f3 = __half22float2(*(const __half2*)&w1.w);
                acc1[8*m+0] += f0.x; acc1[8*m+1] += f0.y;
                acc1[8*m+2] += f1.x; acc1[8*m+3] += f1.y;
                acc1[8*m+4] += f2.x; acc1[8*m+5] += f2.y;
                acc1[8*m+6] += f3.x; acc1[8*m+7] += f3.y;
            }
        }

#pragma unroll
        for (int k = 0; k < 32; ++k) {
            float sp0 = small_ns ? Sl[k * ns + s0] : SgTf[(size_t)k * ns + s0];
            float sp1 = small_ns ? Sl[k * ns + s1] : SgTf[(size_t)k * ns + s1];
            o1[(size_t)k * npairs] = acc0[k] * rs0;
            o0[(size_t)k * npairs] = sp0;
            if (v1) {
                o1[(size_t)k * npairs + 1] = acc1[k] * rs1;
                o0[(size_t)k * npairs + 1] = sp1;
            }
        }
    }
}

extern "C" void kernel_launch(void* const* d_in, const int* in_sizes, int n_in,
                              void* d_out, int out_size, void* d_ws, size_t ws_size,
                              hipStream_t stream) {
    // dict order: [0]=spatial_pos [1]=edge_input [2]=max_dist [3]=spd_table
    //             [4]=edge_table  [5]=edge_dis_weight
    const int* spatial = (const int*)d_in[0];
    const int* edge    = (const int*)d_in[1];
    const void* spd    = d_in[3];
    const void* etab   = d_in[4];
    const void* W      = d_in[5];

    long long npairs = in_sizes[0];
    long long etot   = in_sizes[1];
    int D = (int)(etot / (npairs > 0 ? npairs : 1));
    if (D < 1) D = 1;
    if (D > 16) D = 16;
    int spd_n  = in_sizes[3];
    int ns     = spd_n >> 5;          // spatial vocab (64 here)
    int totalT = D * 1024;

    uint16_t* T16 = (uint16_t*)d_ws;            // D*1024 fp16, pre-swizzled
    float*    spdT = (float*)(T16 + totalT);    // spd_n fp32, transposed [h][s]

    prep<<<(totalT + spd_n + 255) / 256, 256, 0, stream>>>(
        etab, W, spd, T16, spdT, totalT, spd_n);

    int nblk = (int)((npairs + 511) / 512);
    bond2d<<<nblk, 256, 0, stream>>>(spatial, edge, (const float4*)spdT,
                                     (const float4*)T16, (float*)d_out,
                                     (int)npairs, D, ns);
}